// Round 3
// 3099.248 us; speedup vs baseline: 1.0041x; 1.0041x over previous
//
#include <hip/hip_runtime.h>
#include <math.h>

#define NTH 256
#define SB 4   // samples per block

typedef __attribute__((ext_vector_type(8))) short bf16x8;
typedef __attribute__((ext_vector_type(4))) float f32x4;

__device__ __forceinline__ float fast_sigmoid(float x) { return 1.0f / (1.0f + __expf(-x)); }
__device__ __forceinline__ float fast_tanh(float x)    { return 1.0f - 2.0f / (__expf(2.0f * x) + 1.0f); }
__device__ __forceinline__ short f2bf(float x) {
    unsigned u = __float_as_uint(x);
    return (short)((u + 0x7FFFu + ((u >> 16) & 1u)) >> 16);   // RNE
}

// LDS layout (dwords) — R0's exact 11696-dword layout (46.8 KB -> 3 blocks/CU):
//  sU   @0      (4320)  [36 rows][120]  attn outputs -> LSTM inputs
//  SCR  @4320   (6480)  A: 4x1080 | B(pair): 2x3240 | D: sT1(2160)+sTF(540)
//  sH0  @8688   (2112)  h plane 0 (R0's sHf address; final h lands here)
//  sH1  @6480   (2112)  h plane 1 (SCR[2160..4272), dead during C; clobbered by D's sTF — ok)
//  weights/stats @10800..11696

extern "C" __global__ void __launch_bounds__(NTH, 3)
se_kernel(const float* __restrict__ x,
          const float* __restrict__ bn_g, const float* __restrict__ bn_b,
          const float* __restrict__ bn_m, const float* __restrict__ bn_v,
          const float* __restrict__ wq2, const float* __restrict__ wk2,
          const float* __restrict__ wv2, const float* __restrict__ wo2,
          const float* __restrict__ bo2, const float* __restrict__ ln2g,
          const float* __restrict__ ln2b,
          const float* __restrict__ wq4, const float* __restrict__ wk4,
          const float* __restrict__ wv4, const float* __restrict__ wo4,
          const float* __restrict__ bo4, const float* __restrict__ ln4g,
          const float* __restrict__ ln4b,
          const float* __restrict__ w_ih, const float* __restrict__ w_hh,
          const float* __restrict__ b_ih, const float* __restrict__ b_hh,
          const float* __restrict__ cg_w, const float* __restrict__ cg_uw,
          const float* __restrict__ cg_ub,
          const float* __restrict__ w6, const float* __restrict__ b6,
          const float* __restrict__ w7, const float* __restrict__ b7,
          const float* __restrict__ rev_w, const float* __restrict__ rev_b,
          float* __restrict__ out, int Bn)
{
    __shared__ __align__(16) float sm[11696];
    const int tid  = threadIdx.x;
    const int lane = tid & 63;
    const int wv   = tid >> 6;
    const int b0   = blockIdx.x * SB;
    const int nsamp = min(SB, Bn - b0);

    float* sU  = sm;            // 4320
    float* SCR = sm + 4320;     // 6480
    float* sH0 = sm + 8688;     // 2112 : h plane 0 (aliases SCR top, R0's sHf)
    float* sH1 = sm + 6480;     // 2112 : h plane 1 (SCR[2160..4272))
    float* sWQ2 = sm + 10800; float* sWK2 = sm + 10884;
    float* sWV2 = sm + 10968; float* sWO2 = sm + 11052;
    float* sBO2 = sm + 11136; float* sLN2G = sm + 11148; float* sLN2B = sm + 11160;
    float* sKV = sm + 11172; float* sKS = sm + 11256;
    float* sQK = sm + 11268; float* sMU = sm + 11288; float* sRS = sm + 11308;
    float* sST = sm + 11328;
    float* sBO4 = sm + 11336; float* sLN4G = sm + 11456; float* sLN4B = sm + 11576;
    float* sT1 = SCR;           // 2160 (Phase D alias)
    float* sTF = SCR + 2160;    // 540  (Phase D alias; clobbers dead plane 1)

    // ---- Phase 0: stage small shared weights (R0 verbatim) ----
    for (int i = tid; i < 81; i += NTH) {
        sWQ2[i] = wq2[i]; sWK2[i] = wk2[i]; sWV2[i] = wv2[i]; sWO2[i] = wo2[i];
    }
    if (tid < 9) { sBO2[tid] = bo2[tid]; sLN2G[tid] = ln2g[tid]; sLN2B[tid] = ln2b[tid]; }
    for (int i = tid; i < 120; i += NTH) { sBO4[i] = bo4[i]; sLN4G[i] = ln4g[i]; sLN4B[i] = ln4b[i]; }
    __syncthreads();

    // ---- Phase A: lin_attn_2 per sample -> u rows in sU (R0 verbatim) ----
    float* S0 = SCR; float* S1 = SCR + 1080; float* S2 = SCR + 2160; float* S3 = SCR + 3240;
    for (int ss = 0; ss < SB; ++ss) {
        if (ss < nsamp) {
            const int b = b0 + ss;
            for (int i = tid; i < 1080; i += NTH) {
                float xv = x[(size_t)b * 1080 + i];
                S0[i] = (xv - bn_m[i]) * rsqrtf(bn_v[i] + 1e-5f) * bn_g[i] + bn_b[i];
            }
            __syncthreads();
            for (int idx = tid; idx < 1080; idx += NTH) {
                int s = idx / 9, e = idx - s * 9;
                float aq = 0.f, ak = 0.f, av = 0.f;
                #pragma unroll
                for (int d = 0; d < 9; ++d) {
                    float xv = S0[s * 9 + d];
                    aq = fmaf(xv, sWQ2[e * 9 + d], aq);
                    ak = fmaf(xv, sWK2[e * 9 + d], ak);
                    av = fmaf(xv, sWV2[e * 9 + d], av);
                }
                S1[idx] = aq >= 0.f ? aq + 1.f : __expf(aq);
                S2[idx] = ak >= 0.f ? ak + 1.f : __expf(ak);
                S3[idx] = av;
            }
            __syncthreads();
            if (tid < 81) {
                int d = tid / 9, e = tid - d * 9;
                float acc = 0.f;
                for (int s = 0; s < 120; ++s) acc = fmaf(S2[s * 9 + d], S3[s * 9 + e], acc);
                sKV[tid] = acc;
            } else if (tid < 90) {
                int d = tid - 81;
                float acc = 0.f;
                for (int s = 0; s < 120; ++s) acc += S2[s * 9 + d];
                sKS[d] = acc;
            }
            __syncthreads();
            for (int idx = tid; idx < 1080; idx += NTH) {
                int s = idx / 9, e = idx - s * 9;
                float num = 0.f, den = 0.f;
                #pragma unroll
                for (int d = 0; d < 9; ++d) {
                    float qv = S1[s * 9 + d];
                    num = fmaf(qv, sKV[d * 9 + e], num);
                    den = fmaf(qv, sKS[d], den);
                }
                S0[idx] = num / fmaxf(den, 1e-6f);
            }
            __syncthreads();
            for (int idx = tid; idx < 1080; idx += NTH) {
                int s = idx / 9, f = idx - s * 9;
                float acc = sBO2[f] + S0[s * 9 + f];
                #pragma unroll
                for (int e = 0; e < 9; ++e) acc = fmaf(S0[s * 9 + e], sWO2[f * 9 + e], acc);
                S1[idx] = acc;
            }
            __syncthreads();
            if (tid < 120) {
                int s = tid;
                float sum = 0.f, sq = 0.f;
                #pragma unroll
                for (int f = 0; f < 9; ++f) { float v = S1[s * 9 + f]; sum += v; sq = fmaf(v, v, sq); }
                float mu = sum * (1.f / 9.f);
                float rs = rsqrtf(sq * (1.f / 9.f) - mu * mu + 1e-5f);
                #pragma unroll
                for (int f = 0; f < 9; ++f)
                    sU[(ss * 9 + f) * 120 + s] = (S1[s * 9 + f] - mu) * rs * sLN2G[f] + sLN2B[f];
            }
        }
        __syncthreads();
    }

    // ---- Phase B: lin_attn_4 per sample PAIR (R0 verbatim) ----
    for (int p = 0; p < 2; ++p) {
        if (tid < 180) {
            int sp = tid / 90, r2 = tid - sp * 90;
            int m = r2 / 30, eq = r2 - m * 30, e0 = eq * 4;
            const float* W = (m == 0) ? wq4 : (m == 1) ? wk4 : wv4;
            const float* uB = sU + (p * 2 + sp) * 1080;
            float acc[4][9];
            #pragma unroll
            for (int r = 0; r < 4; ++r)
                #pragma unroll
                for (int v = 0; v < 9; ++v) acc[r][v] = 0.f;
            for (int dq = 0; dq < 30; ++dq) {
                float4 u[9];
                #pragma unroll
                for (int v = 0; v < 9; ++v) u[v] = *(const float4*)&uB[v * 120 + dq * 4];
                #pragma unroll
                for (int r = 0; r < 4; ++r) {
                    float4 w = *(const float4*)&W[(e0 + r) * 120 + dq * 4];
                    #pragma unroll
                    for (int v = 0; v < 9; ++v) {
                        acc[r][v] = fmaf(w.x, u[v].x, acc[r][v]);
                        acc[r][v] = fmaf(w.y, u[v].y, acc[r][v]);
                        acc[r][v] = fmaf(w.z, u[v].z, acc[r][v]);
                        acc[r][v] = fmaf(w.w, u[v].w, acc[r][v]);
                    }
                }
            }
            float* dst = SCR + sp * 3240 + m * 1080;
            #pragma unroll
            for (int v = 0; v < 9; ++v) {
                float4 o;
                o.x = acc[0][v]; o.y = acc[1][v]; o.z = acc[2][v]; o.w = acc[3][v];
                if (m != 2) {
                    o.x = o.x >= 0.f ? o.x + 1.f : __expf(o.x);
                    o.y = o.y >= 0.f ? o.y + 1.f : __expf(o.y);
                    o.z = o.z >= 0.f ? o.z + 1.f : __expf(o.z);
                    o.w = o.w >= 0.f ? o.w + 1.f : __expf(o.w);
                }
                *(float4*)&dst[v * 120 + e0] = o;
            }
        }
        __syncthreads();
        if (tid < 18) {
            int sp = tid / 9, v = tid - sp * 9;
            const float4* q4 = (const float4*)(SCR + sp * 3240 + v * 120);
            const float4* k4 = (const float4*)(SCR + sp * 3240 + 1080 + v * 120);
            float acc = 0.f;
            for (int i = 0; i < 30; ++i) {
                float4 a = q4[i], bb = k4[i];
                acc = fmaf(a.x, bb.x, acc); acc = fmaf(a.y, bb.y, acc);
                acc = fmaf(a.z, bb.z, acc); acc = fmaf(a.w, bb.w, acc);
            }
            sQK[tid] = acc;
        }
        __syncthreads();
        for (int idx = tid; idx < 540; idx += NTH) {
            int sp = idx / 270, off = idx - sp * 270;
            int v = off / 30;
            float qk = sQK[sp * 9 + v];
            float s = qk / fmaxf(qk, 1e-6f);
            float4* pv = (float4*)(SCR + sp * 3240 + 2160) + off;
            float4 t = *pv;
            t.x *= s; t.y *= s; t.z *= s; t.w *= s;
            *pv = t;
        }
        __syncthreads();
        if (tid < 120) {
            int sp = tid / 60, ep = tid - sp * 60;
            int e0 = ep * 2;
            const float* vB = SCR + sp * 3240 + 2160;
            float acc[2][9];
            #pragma unroll
            for (int r = 0; r < 2; ++r)
                #pragma unroll
                for (int v = 0; v < 9; ++v) acc[r][v] = 0.f;
            const float* w0p = &wo4[e0 * 120];
            const float* w1p = &wo4[(e0 + 1) * 120];
            for (int dq = 0; dq < 30; ++dq) {
                float4 wA = *(const float4*)&w0p[dq * 4];
                float4 wB = *(const float4*)&w1p[dq * 4];
                #pragma unroll
                for (int v = 0; v < 9; ++v) {
                    float4 u = *(const float4*)&vB[v * 120 + dq * 4];
                    acc[0][v] = fmaf(wA.x, u.x, acc[0][v]); acc[0][v] = fmaf(wA.y, u.y, acc[0][v]);
                    acc[0][v] = fmaf(wA.z, u.z, acc[0][v]); acc[0][v] = fmaf(wA.w, u.w, acc[0][v]);
                    acc[1][v] = fmaf(wB.x, u.x, acc[1][v]); acc[1][v] = fmaf(wB.y, u.y, acc[1][v]);
                    acc[1][v] = fmaf(wB.z, u.z, acc[1][v]); acc[1][v] = fmaf(wB.w, u.w, acc[1][v]);
                }
            }
            float* Y = SCR + sp * 3240;
            #pragma unroll
            for (int v = 0; v < 9; ++v) {
                float o0 = vB[v * 120 + e0], o1 = vB[v * 120 + e0 + 1];
                Y[v * 120 + e0]     = acc[0][v] + sBO4[e0]     + o0;
                Y[v * 120 + e0 + 1] = acc[1][v] + sBO4[e0 + 1] + o1;
            }
        }
        __syncthreads();
        if (tid < 18) {
            int sp = tid / 9, v = tid - sp * 9;
            const float* Y = SCR + sp * 3240 + v * 120;
            float sum = 0.f, sq = 0.f;
            for (int e = 0; e < 120; ++e) { float t = Y[e]; sum += t; sq = fmaf(t, t, sq); }
            float mu = sum * (1.f / 120.f);
            sMU[tid] = mu;
            sRS[tid] = rsqrtf(sq * (1.f / 120.f) - mu * mu + 1e-5f);
        }
        __syncthreads();
        for (int idx = tid; idx < 540; idx += NTH) {
            int sp = idx / 270, off = idx - sp * 270;
            int v = off / 30, qq = off - v * 30;
            const float* Y = SCR + sp * 3240;
            float4 y = *(const float4*)&Y[v * 120 + qq * 4];
            float4 g = *(const float4*)&sLN4G[qq * 4];
            float4 bb = *(const float4*)&sLN4B[qq * 4];
            float mu = sMU[sp * 9 + v], rs = sRS[sp * 9 + v];
            float4 o;
            o.x = (y.x - mu) * rs * g.x + bb.x;
            o.y = (y.y - mu) * rs * g.y + bb.y;
            o.z = (y.z - mu) * rs * g.z + bb.z;
            o.w = (y.w - mu) * rs * g.w + bb.w;
            *(float4*)&sU[((p * 2 + sp) * 9 + v) * 120 + qq * 4] = o;
        }
        __syncthreads();
    }

    // ---- Phase C: CGLSTM via MFMA — double-buffered h planes, 1 barrier/step.
    //      Identical arithmetic to R0 (same reads/values/writes); only the
    //      plane h lives in alternates, so reads(t-1-plane) and writes(t-plane)
    //      never touch the same memory within a step.
    for (int i = tid; i < 2112; i += NTH) sH0[i] = 0.f;   // h0 = 0 (plane 0)
    __syncthreads();

    const int c = lane & 15, q = lane >> 4;
    bf16x8 bfr[8]; float wxv[8], bsv[8];
    int grow[4] = {0, 0, 0, 0}; int pcol = 0;
    if (wv < 3) {
        // Probe 1: A(m,0)=m, B(0,n)=1  -> D slot value = its ROW
        // Probe 2: A(m,0)=1, B(0,n)=n  -> D slot value = its COLUMN
        bf16x8 pa, pb, pa2, pb2;
        #pragma unroll
        for (int j = 0; j < 8; ++j) { pa[j] = 0; pb[j] = 0; pa2[j] = 0; pb2[j] = 0; }
        if (q == 0) {
            pa[0]  = f2bf((float)c); pb[0]  = f2bf(1.0f);
            pa2[0] = f2bf(1.0f);     pb2[0] = f2bf((float)c);
        }
        f32x4 zc; zc[0] = zc[1] = zc[2] = zc[3] = 0.f;
        f32x4 prr = __builtin_amdgcn_mfma_f32_16x16x32_bf16(pa,  pb,  zc, 0, 0, 0);
        f32x4 pcc = __builtin_amdgcn_mfma_f32_16x16x32_bf16(pa2, pb2, zc, 0, 0, 0);
        #pragma unroll
        for (int r = 0; r < 4; ++r) grow[r] = wv * 16 + (int)(prr[r] + 0.5f);
        pcol = (int)(pcc[0] + 0.5f);

        // Loop-invariant B-fragments + rank-1 x/bias constants, per probed column.
        #pragma unroll
        for (int T = 0; T < 8; ++T) {
            int gate = T >> 1, kk = ((T & 1) << 4) + pcol;
            const float* wr; float wx, bs;
            if (gate < 3) {
                int n = gate * 32 + kk;
                wr = &w_hh[n * 32]; wx = w_ih[n]; bs = b_ih[n] + b_hh[n];
            } else {
                wr = &cg_uw[kk * 32]; wx = cg_w[kk]; bs = cg_ub[kk];
            }
            bf16x8 tv;
            #pragma unroll
            for (int j = 0; j < 8; ++j) tv[j] = f2bf(wr[q * 8 + j]);
            bfr[T] = tv; wxv[T] = wx; bsv[T] = bs;
        }
    }
    float cst[8];
    #pragma unroll
    for (int i = 0; i < 8; ++i) cst[i] = 0.f;
    const int live9 = nsamp * 9;
    const float* ar0 = &sH0[(wv * 16 + c) * 44 + q * 8];
    const float* ar1 = &sH1[(wv * 16 + c) * 44 + q * 8];

// One LSTM step: read h(t-1) from plane RP, write h(t) into plane WPL.
// Planes are disjoint -> a single end-of-step barrier suffices.
#define LSTM_STEP(RP, WPL, XARR)                                               \
    if (wv < 3) {                                                              \
        float4 hA = *(const float4*)(RP);                                      \
        float4 hB = *(const float4*)((RP) + 4);                                \
        bf16x8 af;                                                             \
        af[0] = f2bf(hA.x); af[1] = f2bf(hA.y);                                \
        af[2] = f2bf(hA.z); af[3] = f2bf(hA.w);                                \
        af[4] = f2bf(hB.x); af[5] = f2bf(hB.y);                                \
        af[6] = f2bf(hB.z); af[7] = f2bf(hB.w);                                \
        f32x4 acc[8];                                                          \
        _Pragma("unroll")                                                      \
        for (int T = 0; T < 8; ++T) {                                          \
            f32x4 ci;                                                          \
            _Pragma("unroll")                                                  \
            for (int r = 0; r < 4; ++r) ci[r] = fmaf(wxv[T], XARR[r], bsv[T]); \
            acc[T] = __builtin_amdgcn_mfma_f32_16x16x32_bf16(af, bfr[T], ci, 0, 0, 0); \
        }                                                                      \
        _Pragma("unroll")                                                      \
        for (int kh = 0; kh < 2; ++kh) {                                       \
            _Pragma("unroll")                                                  \
            for (int r = 0; r < 4; ++r) {                                      \
                float si  = fast_sigmoid(acc[kh][r]);                          \
                float sf  = fast_sigmoid(acc[2 + kh][r]);                      \
                float tg  = fast_tanh(acc[4 + kh][r]);                         \
                float sgc = fast_sigmoid(acc[6 + kh][r]);                      \
                float cn = fmaf(sf, cst[kh * 4 + r], si * tg);                 \
                cst[kh * 4 + r] = cn;                                          \
                (WPL)[grow[r] * 44 + (kh << 4) + pcol] = sgc * fast_tanh(cn);  \
            }                                                                  \
        }                                                                      \
    }                                                                          \
    __syncthreads();

    for (int t = 0; t < 120; t += 2) {
        float xa[4], xb[4];
        if (wv < 3) {
            #pragma unroll
            for (int r = 0; r < 4; ++r) {
                float2 xv;
                if (grow[r] < live9) xv = *(const float2*)&sU[grow[r] * 120 + t];
                else { xv.x = 0.f; xv.y = 0.f; }
                xa[r] = xv.x; xb[r] = xv.y;
            }
        }
        LSTM_STEP(ar0, sH1, xa)     // even step: plane0 -> plane1
        LSTM_STEP(ar1, sH0, xb)     // odd step:  plane1 -> plane0
    }
    // final h (t=119) lives in plane 0 (sH0 = R0's sHf address)

    // cglstm_out (output 0) straight from the LDS h-plane (layout-independent)
    for (int idx = tid; idx < SB * 288; idx += NTH) {
        int ssd = idx / 288, r = idx - ssd * 288;
        if (ssd < nsamp) {
            int v = r >> 5, k = r & 31;
            out[(size_t)(b0 + ssd) * 288 + r] = sH0[(ssd * 9 + v) * 44 + k];
        }
    }

    // ---- Phase D: conv6(softplus) -> conv7(tanh) -> RevIN (R0 verbatim) ----
    for (int idx = tid; idx < SB * 540; idx += NTH) {
        int ssd = idx / 540, rem = idx - ssd * 540;
        int v = rem / 60, j = rem - v * 60;
        if (ssd < nsamp) {
            float acc = b6[j];
            const float4* wr4 = (const float4*)&w6[j * 32];
            const float4* hv = (const float4*)&sH0[(ssd * 9 + v) * 44];
            #pragma unroll
            for (int qq = 0; qq < 8; ++qq) {
                float4 w = wr4[qq], h = hv[qq];
                acc = fmaf(w.x, h.x, acc); acc = fmaf(w.y, h.y, acc);
                acc = fmaf(w.z, h.z, acc); acc = fmaf(w.w, h.w, acc);
            }
            sT1[idx] = acc > 15.f ? acc : log1pf(__expf(acc));
        }
    }
    __syncthreads();
    for (int idx = tid; idx < SB * 135; idx += NTH) {
        int ssd = idx / 135, rem = idx - ssd * 135;
        int v = rem / 15, f = rem - v * 15;
        if (ssd < nsamp) {
            float acc = b7[f];
            const float4* wr = (const float4*)&w7[f * 60];
            const float4* tv = (const float4*)&sT1[ssd * 540 + v * 60];
            #pragma unroll
            for (int qq = 0; qq < 15; ++qq) {
                float4 w = wr[qq], h = tv[qq];
                acc = fmaf(w.x, h.x, acc); acc = fmaf(w.y, h.y, acc);
                acc = fmaf(w.z, h.z, acc); acc = fmaf(w.w, h.w, acc);
            }
            sTF[idx] = fast_tanh(acc);
        }
    }
    __syncthreads();
    if (tid < SB && tid < nsamp) {
        const float* tf = &sTF[tid * 135];
        float sum = 0.f;
        for (int i = 0; i < 135; ++i) sum += tf[i];
        float mu = sum * (1.f / 135.f);
        float sq = 0.f;
        for (int i = 0; i < 135; ++i) { float d = tf[i] - mu; sq = fmaf(d, d, sq); }
        float sd = sqrtf(sq * (1.f / 134.f));  // ddof=1
        sST[tid * 2]     = mu;
        sST[tid * 2 + 1] = 1.f / fmaxf(sd, 1e-5f);
    }
    __syncthreads();
    const size_t encbase = (size_t)Bn * 288;
    for (int idx = tid; idx < SB * 135; idx += NTH) {
        int ssd = idx / 135, j = idx - ssd * 135;
        if (ssd < nsamp) {
            int qq = j / 15, pp = j - qq * 15;
            float val = (sTF[ssd * 135 + pp * 9 + qq] - sST[ssd * 2]) * sST[ssd * 2 + 1] * rev_w[j] + rev_b[j];
            out[encbase + (size_t)(b0 + ssd) * 135 + j] = val;
        }
    }
}

extern "C" void kernel_launch(void* const* d_in, const int* in_sizes, int n_in,
                              void* d_out, int out_size, void* d_ws, size_t ws_size,
                              hipStream_t stream) {
    const float* x    = (const float*)d_in[0];
    const float* bn_g = (const float*)d_in[1];
    const float* bn_b = (const float*)d_in[2];
    const float* bn_m = (const float*)d_in[3];
    const float* bn_v = (const float*)d_in[4];
    const float* wq2  = (const float*)d_in[5];
    const float* wk2  = (const float*)d_in[6];
    const float* wv2  = (const float*)d_in[7];
    const float* wo2  = (const float*)d_in[8];
    const float* bo2  = (const float*)d_in[9];
    const float* ln2g = (const float*)d_in[10];
    const float* ln2b = (const float*)d_in[11];
    const float* wq4  = (const float*)d_in[12];
    const float* wk4  = (const float*)d_in[13];
    const float* wv4  = (const float*)d_in[14];
    const float* wo4  = (const float*)d_in[15];
    const float* bo4  = (const float*)d_in[16];
    const float* ln4g = (const float*)d_in[17];
    const float* ln4b = (const float*)d_in[18];
    const float* w_ih = (const float*)d_in[19];
    const float* w_hh = (const float*)d_in[20];
    const float* b_ih = (const float*)d_in[21];
    const float* b_hh = (const float*)d_in[22];
    const float* cg_w = (const float*)d_in[23];
    const float* cg_uw= (const float*)d_in[24];
    const float* cg_ub= (const float*)d_in[25];
    const float* w6   = (const float*)d_in[26];
    const float* b6   = (const float*)d_in[27];
    const float* w7   = (const float*)d_in[28];
    const float* b7   = (const float*)d_in[29];
    const float* rev_w= (const float*)d_in[30];
    const float* rev_b= (const float*)d_in[31];

    int Bn = in_sizes[0] / 1080;
    int grid = (Bn + SB - 1) / SB;
    hipLaunchKernelGGL(se_kernel, dim3(grid), dim3(NTH), 0, stream,
                       x, bn_g, bn_b, bn_m, bn_v, wq2, wk2, wv2, wo2, bo2, ln2g, ln2b,
                       wq4, wk4, wv4, wo4, bo4, ln4g, ln4b,
                       w_ih, w_hh, b_ih, b_hh, cg_w, cg_uw, cg_ub,
                       w6, b6, w7, b7, rev_w, rev_b,
                       (float*)d_out, Bn);
}

// Round 4
// 2923.457 us; speedup vs baseline: 1.0645x; 1.0601x over previous
//
#include <hip/hip_runtime.h>
#include <math.h>

#define NTH 256
#define SB 4   // samples per block

typedef __attribute__((ext_vector_type(8))) short bf16x8;
typedef __attribute__((ext_vector_type(4))) float f32x4;

__device__ __forceinline__ float fast_sigmoid(float x) { return 1.0f / (1.0f + __expf(-x)); }
__device__ __forceinline__ float fast_tanh(float x)    { return 1.0f - 2.0f / (__expf(2.0f * x) + 1.0f); }
__device__ __forceinline__ short f2bf(float x) {
    unsigned u = __float_as_uint(x);
    return (short)((u + 0x7FFFu + ((u >> 16) & 1u)) >> 16);   // RNE
}

// LDS layout (dwords) — 9516 dw = 38,064 B -> 4 blocks/CU at the HW level
// (launch_bounds kept at (256,3), unchanged from R3, to isolate the repack):
//  sU   @0      (4320)  [36 rows][120]; Phase D aliases sT1/sTF here (sU dead then)
//  SCR  @4320   (4320)  A: S0..S3 | B: V[2][1080]+Y[2][1080] | C: sH0(2112)+sH1(2112)
//  weights/stats @8640..9516
extern "C" __global__ void __launch_bounds__(NTH, 3)
se_kernel(const float* __restrict__ x,
          const float* __restrict__ bn_g, const float* __restrict__ bn_b,
          const float* __restrict__ bn_m, const float* __restrict__ bn_v,
          const float* __restrict__ wq2, const float* __restrict__ wk2,
          const float* __restrict__ wv2, const float* __restrict__ wo2,
          const float* __restrict__ bo2, const float* __restrict__ ln2g,
          const float* __restrict__ ln2b,
          const float* __restrict__ wq4, const float* __restrict__ wk4,
          const float* __restrict__ wv4, const float* __restrict__ wo4,
          const float* __restrict__ bo4, const float* __restrict__ ln4g,
          const float* __restrict__ ln4b,
          const float* __restrict__ w_ih, const float* __restrict__ w_hh,
          const float* __restrict__ b_ih, const float* __restrict__ b_hh,
          const float* __restrict__ cg_w, const float* __restrict__ cg_uw,
          const float* __restrict__ cg_ub,
          const float* __restrict__ w6, const float* __restrict__ b6,
          const float* __restrict__ w7, const float* __restrict__ b7,
          const float* __restrict__ rev_w, const float* __restrict__ rev_b,
          float* __restrict__ out, int Bn)
{
    __shared__ __align__(16) float sm[9516];
    const int tid  = threadIdx.x;
    const int lane = tid & 63;
    const int wv   = tid >> 6;
    const int b0   = blockIdx.x * SB;
    const int nsamp = min(SB, Bn - b0);

    float* sU  = sm;            // 4320
    float* SCR = sm + 4320;     // 4320
    float* sWQ2 = sm + 8640; float* sWK2 = sm + 8724;
    float* sWV2 = sm + 8808; float* sWO2 = sm + 8892;
    float* sBO2 = sm + 8976; float* sLN2G = sm + 8988; float* sLN2B = sm + 9000;
    float* sKV = sm + 9012; float* sKS = sm + 9096;
    float* sMU = sm + 9108; float* sRS = sm + 9128;
    float* sST = sm + 9148;
    float* sBO4 = sm + 9156; float* sLN4G = sm + 9276; float* sLN4B = sm + 9396;
    float* sH0 = SCR;           // 2112 : h plane 0 (final h lands here)
    float* sH1 = SCR + 2112;    // 2112 : h plane 1 (ends 4224 <= 4320)
    float* sT1 = sU;            // 2160 (Phase D alias; sU dead after C)
    float* sTF = sU + 2160;     // 540  (Phase D alias)

    // ---- Phase 0: stage small shared weights (R0 verbatim, new addresses) ----
    for (int i = tid; i < 81; i += NTH) {
        sWQ2[i] = wq2[i]; sWK2[i] = wk2[i]; sWV2[i] = wv2[i]; sWO2[i] = wo2[i];
    }
    if (tid < 9) { sBO2[tid] = bo2[tid]; sLN2G[tid] = ln2g[tid]; sLN2B[tid] = ln2b[tid]; }
    for (int i = tid; i < 120; i += NTH) { sBO4[i] = bo4[i]; sLN4G[i] = ln4g[i]; sLN4B[i] = ln4b[i]; }
    __syncthreads();

    // ---- Phase A: lin_attn_2 per sample -> u rows in sU (R0 verbatim) ----
    float* S0 = SCR; float* S1 = SCR + 1080; float* S2 = SCR + 2160; float* S3 = SCR + 3240;
    for (int ss = 0; ss < SB; ++ss) {
        if (ss < nsamp) {
            const int b = b0 + ss;
            for (int i = tid; i < 1080; i += NTH) {
                float xv = x[(size_t)b * 1080 + i];
                S0[i] = (xv - bn_m[i]) * rsqrtf(bn_v[i] + 1e-5f) * bn_g[i] + bn_b[i];
            }
            __syncthreads();
            for (int idx = tid; idx < 1080; idx += NTH) {
                int s = idx / 9, e = idx - s * 9;
                float aq = 0.f, ak = 0.f, av = 0.f;
                #pragma unroll
                for (int d = 0; d < 9; ++d) {
                    float xv = S0[s * 9 + d];
                    aq = fmaf(xv, sWQ2[e * 9 + d], aq);
                    ak = fmaf(xv, sWK2[e * 9 + d], ak);
                    av = fmaf(xv, sWV2[e * 9 + d], av);
                }
                S1[idx] = aq >= 0.f ? aq + 1.f : __expf(aq);
                S2[idx] = ak >= 0.f ? ak + 1.f : __expf(ak);
                S3[idx] = av;
            }
            __syncthreads();
            if (tid < 81) {
                int d = tid / 9, e = tid - d * 9;
                float acc = 0.f;
                for (int s = 0; s < 120; ++s) acc = fmaf(S2[s * 9 + d], S3[s * 9 + e], acc);
                sKV[tid] = acc;
            } else if (tid < 90) {
                int d = tid - 81;
                float acc = 0.f;
                for (int s = 0; s < 120; ++s) acc += S2[s * 9 + d];
                sKS[d] = acc;
            }
            __syncthreads();
            for (int idx = tid; idx < 1080; idx += NTH) {
                int s = idx / 9, e = idx - s * 9;
                float num = 0.f, den = 0.f;
                #pragma unroll
                for (int d = 0; d < 9; ++d) {
                    float qv = S1[s * 9 + d];
                    num = fmaf(qv, sKV[d * 9 + e], num);
                    den = fmaf(qv, sKS[d], den);
                }
                S0[idx] = num / fmaxf(den, 1e-6f);
            }
            __syncthreads();
            for (int idx = tid; idx < 1080; idx += NTH) {
                int s = idx / 9, f = idx - s * 9;
                float acc = sBO2[f] + S0[s * 9 + f];
                #pragma unroll
                for (int e = 0; e < 9; ++e) acc = fmaf(S0[s * 9 + e], sWO2[f * 9 + e], acc);
                S1[idx] = acc;
            }
            __syncthreads();
            if (tid < 120) {
                int s = tid;
                float sum = 0.f, sq = 0.f;
                #pragma unroll
                for (int f = 0; f < 9; ++f) { float v = S1[s * 9 + f]; sum += v; sq = fmaf(v, v, sq); }
                float mu = sum * (1.f / 9.f);
                float rs = rsqrtf(sq * (1.f / 9.f) - mu * mu + 1e-5f);
                #pragma unroll
                for (int f = 0; f < 9; ++f)
                    sU[(ss * 9 + f) * 120 + s] = (S1[s * 9 + f] - mu) * rs * sLN2G[f] + sLN2B[f];
            }
        }
        __syncthreads();
    }

    // ---- Phase B: lin_attn_4 per sample PAIR; Q/K/qk/scale deleted.
    //      Proof: R0 computed s = qk/max(qk,1e-6). qk is a sum of 120 strictly
    //      positive terms (phi=elu+1>0), so qk>=1e-6 and s = qk/qk = 1.0f
    //      exactly (IEEE x/x=1). R0 then did V *= 1.0f — an exact no-op. The
    //      V-chain and Y-chain below keep R0's exact per-element fmaf order
    //      and residual associativity, so Phase-B output is bit-identical.
    for (int p = 0; p < 2; ++p) {
        float* V0 = SCR;               // V[2][1080]
        float* Y0 = SCR + 2160;        // Y[2][1080]
        if (tid < 120) {               // V rows e0,e0+1 for sample sp of the pair
            int sp = tid / 60, ep = tid - sp * 60;
            int e0 = ep * 2;
            const float* uB = sU + (p * 2 + sp) * 1080;
            float acc[2][9];
            #pragma unroll
            for (int r = 0; r < 2; ++r)
                #pragma unroll
                for (int v = 0; v < 9; ++v) acc[r][v] = 0.f;
            const float* w0p = &wv4[e0 * 120];
            const float* w1p = &wv4[(e0 + 1) * 120];
            for (int dq = 0; dq < 30; ++dq) {
                float4 wA = *(const float4*)&w0p[dq * 4];
                float4 wB = *(const float4*)&w1p[dq * 4];
                #pragma unroll
                for (int v = 0; v < 9; ++v) {
                    float4 u = *(const float4*)&uB[v * 120 + dq * 4];
                    acc[0][v] = fmaf(wA.x, u.x, acc[0][v]); acc[0][v] = fmaf(wA.y, u.y, acc[0][v]);
                    acc[0][v] = fmaf(wA.z, u.z, acc[0][v]); acc[0][v] = fmaf(wA.w, u.w, acc[0][v]);
                    acc[1][v] = fmaf(wB.x, u.x, acc[1][v]); acc[1][v] = fmaf(wB.y, u.y, acc[1][v]);
                    acc[1][v] = fmaf(wB.z, u.z, acc[1][v]); acc[1][v] = fmaf(wB.w, u.w, acc[1][v]);
                }
            }
            float* dst = V0 + sp * 1080;
            #pragma unroll
            for (int v = 0; v < 9; ++v) {
                dst[v * 120 + e0]     = acc[0][v];
                dst[v * 120 + e0 + 1] = acc[1][v];
            }
        }
        __syncthreads();
        if (tid < 120) {               // Y rows e0,e0+1 (R0's wo4 pass, verbatim chain)
            int sp = tid / 60, ep = tid - sp * 60;
            int e0 = ep * 2;
            const float* vB = V0 + sp * 1080;
            float acc[2][9];
            #pragma unroll
            for (int r = 0; r < 2; ++r)
                #pragma unroll
                for (int v = 0; v < 9; ++v) acc[r][v] = 0.f;
            const float* w0p = &wo4[e0 * 120];
            const float* w1p = &wo4[(e0 + 1) * 120];
            for (int dq = 0; dq < 30; ++dq) {
                float4 wA = *(const float4*)&w0p[dq * 4];
                float4 wB = *(const float4*)&w1p[dq * 4];
                #pragma unroll
                for (int v = 0; v < 9; ++v) {
                    float4 u = *(const float4*)&vB[v * 120 + dq * 4];
                    acc[0][v] = fmaf(wA.x, u.x, acc[0][v]); acc[0][v] = fmaf(wA.y, u.y, acc[0][v]);
                    acc[0][v] = fmaf(wA.z, u.z, acc[0][v]); acc[0][v] = fmaf(wA.w, u.w, acc[0][v]);
                    acc[1][v] = fmaf(wB.x, u.x, acc[1][v]); acc[1][v] = fmaf(wB.y, u.y, acc[1][v]);
                    acc[1][v] = fmaf(wB.z, u.z, acc[1][v]); acc[1][v] = fmaf(wB.w, u.w, acc[1][v]);
                }
            }
            float* Y = Y0 + sp * 1080;
            #pragma unroll
            for (int v = 0; v < 9; ++v) {
                float o0 = vB[v * 120 + e0], o1 = vB[v * 120 + e0 + 1];
                Y[v * 120 + e0]     = acc[0][v] + sBO4[e0]     + o0;
                Y[v * 120 + e0 + 1] = acc[1][v] + sBO4[e0 + 1] + o1;
            }
        }
        __syncthreads();
        if (tid < 18) {                // LN stats (R0 verbatim chain)
            int sp = tid / 9, v = tid - sp * 9;
            const float* Y = Y0 + sp * 1080 + v * 120;
            float sum = 0.f, sq = 0.f;
            for (int e = 0; e < 120; ++e) { float t = Y[e]; sum += t; sq = fmaf(t, t, sq); }
            float mu = sum * (1.f / 120.f);
            sMU[tid] = mu;
            sRS[tid] = rsqrtf(sq * (1.f / 120.f) - mu * mu + 1e-5f);
        }
        __syncthreads();
        for (int idx = tid; idx < 540; idx += NTH) {   // LN apply (R0 verbatim chain)
            int sp = idx / 270, off = idx - sp * 270;
            int v = off / 30, qq = off - v * 30;
            const float* Y = Y0 + sp * 1080;
            float4 y = *(const float4*)&Y[v * 120 + qq * 4];
            float4 g = *(const float4*)&sLN4G[qq * 4];
            float4 bb = *(const float4*)&sLN4B[qq * 4];
            float mu = sMU[sp * 9 + v], rs = sRS[sp * 9 + v];
            float4 o;
            o.x = (y.x - mu) * rs * g.x + bb.x;
            o.y = (y.y - mu) * rs * g.y + bb.y;
            o.z = (y.z - mu) * rs * g.z + bb.z;
            o.w = (y.w - mu) * rs * g.w + bb.w;
            *(float4*)&sU[((p * 2 + sp) * 9 + v) * 120 + qq * 4] = o;
        }
        __syncthreads();
    }

    // ---- Phase C: CGLSTM via MFMA — R3-proven double-buffered planes ----
    for (int i = tid; i < 2112; i += NTH) sH0[i] = 0.f;   // h0 = 0 (plane 0)
    __syncthreads();

    const int c = lane & 15, q = lane >> 4;
    bf16x8 bfr[8]; float wxv[8], bsv[8];
    int grow[4] = {0, 0, 0, 0}; int pcol = 0;
    if (wv < 3) {
        // Probe 1: A(m,0)=m, B(0,n)=1  -> D slot value = its ROW
        // Probe 2: A(m,0)=1, B(0,n)=n  -> D slot value = its COLUMN
        bf16x8 pa, pb, pa2, pb2;
        #pragma unroll
        for (int j = 0; j < 8; ++j) { pa[j] = 0; pb[j] = 0; pa2[j] = 0; pb2[j] = 0; }
        if (q == 0) {
            pa[0]  = f2bf((float)c); pb[0]  = f2bf(1.0f);
            pa2[0] = f2bf(1.0f);     pb2[0] = f2bf((float)c);
        }
        f32x4 zc; zc[0] = zc[1] = zc[2] = zc[3] = 0.f;
        f32x4 prr = __builtin_amdgcn_mfma_f32_16x16x32_bf16(pa,  pb,  zc, 0, 0, 0);
        f32x4 pcc = __builtin_amdgcn_mfma_f32_16x16x32_bf16(pa2, pb2, zc, 0, 0, 0);
        #pragma unroll
        for (int r = 0; r < 4; ++r) grow[r] = wv * 16 + (int)(prr[r] + 0.5f);
        pcol = (int)(pcc[0] + 0.5f);

        #pragma unroll
        for (int T = 0; T < 8; ++T) {
            int gate = T >> 1, kk = ((T & 1) << 4) + pcol;
            const float* wr; float wx, bs;
            if (gate < 3) {
                int n = gate * 32 + kk;
                wr = &w_hh[n * 32]; wx = w_ih[n]; bs = b_ih[n] + b_hh[n];
            } else {
                wr = &cg_uw[kk * 32]; wx = cg_w[kk]; bs = cg_ub[kk];
            }
            bf16x8 tv;
            #pragma unroll
            for (int j = 0; j < 8; ++j) tv[j] = f2bf(wr[q * 8 + j]);
            bfr[T] = tv; wxv[T] = wx; bsv[T] = bs;
        }
    }
    float cst[8];
    #pragma unroll
    for (int i = 0; i < 8; ++i) cst[i] = 0.f;
    const int live9 = nsamp * 9;
    const float* ar0 = &sH0[(wv * 16 + c) * 44 + q * 8];
    const float* ar1 = &sH1[(wv * 16 + c) * 44 + q * 8];

#define LSTM_STEP(RP, WPL, XARR)                                               \
    if (wv < 3) {                                                              \
        float4 hA = *(const float4*)(RP);                                      \
        float4 hB = *(const float4*)((RP) + 4);                                \
        bf16x8 af;                                                             \
        af[0] = f2bf(hA.x); af[1] = f2bf(hA.y);                                \
        af[2] = f2bf(hA.z); af[3] = f2bf(hA.w);                                \
        af[4] = f2bf(hB.x); af[5] = f2bf(hB.y);                                \
        af[6] = f2bf(hB.z); af[7] = f2bf(hB.w);                                \
        f32x4 acc[8];                                                          \
        _Pragma("unroll")                                                      \
        for (int T = 0; T < 8; ++T) {                                          \
            f32x4 ci;                                                          \
            _Pragma("unroll")                                                  \
            for (int r = 0; r < 4; ++r) ci[r] = fmaf(wxv[T], XARR[r], bsv[T]); \
            acc[T] = __builtin_amdgcn_mfma_f32_16x16x32_bf16(af, bfr[T], ci, 0, 0, 0); \
        }                                                                      \
        _Pragma("unroll")                                                      \
        for (int kh = 0; kh < 2; ++kh) {                                       \
            _Pragma("unroll")                                                  \
            for (int r = 0; r < 4; ++r) {                                      \
                float si  = fast_sigmoid(acc[kh][r]);                          \
                float sf  = fast_sigmoid(acc[2 + kh][r]);                      \
                float tg  = fast_tanh(acc[4 + kh][r]);                         \
                float sgc = fast_sigmoid(acc[6 + kh][r]);                      \
                float cn = fmaf(sf, cst[kh * 4 + r], si * tg);                 \
                cst[kh * 4 + r] = cn;                                          \
                (WPL)[grow[r] * 44 + (kh << 4) + pcol] = sgc * fast_tanh(cn);  \
            }                                                                  \
        }                                                                      \
    }                                                                          \
    __syncthreads();

    for (int t = 0; t < 120; t += 2) {
        float xa[4], xb[4];
        if (wv < 3) {
            #pragma unroll
            for (int r = 0; r < 4; ++r) {
                float2 xv;
                if (grow[r] < live9) xv = *(const float2*)&sU[grow[r] * 120 + t];
                else { xv.x = 0.f; xv.y = 0.f; }
                xa[r] = xv.x; xb[r] = xv.y;
            }
        }
        LSTM_STEP(ar0, sH1, xa)     // even step: plane0 -> plane1
        LSTM_STEP(ar1, sH0, xb)     // odd step:  plane1 -> plane0
    }
    // final h (t=119) lives in plane 0 (sH0)

    // cglstm_out (output 0) straight from the LDS h-plane
    for (int idx = tid; idx < SB * 288; idx += NTH) {
        int ssd = idx / 288, r = idx - ssd * 288;
        if (ssd < nsamp) {
            int v = r >> 5, k = r & 31;
            out[(size_t)(b0 + ssd) * 288 + r] = sH0[(ssd * 9 + v) * 44 + k];
        }
    }

    // ---- Phase D: conv6(softplus) -> conv7(tanh) -> RevIN (R0 verbatim) ----
    for (int idx = tid; idx < SB * 540; idx += NTH) {
        int ssd = idx / 540, rem = idx - ssd * 540;
        int v = rem / 60, j = rem - v * 60;
        if (ssd < nsamp) {
            float acc = b6[j];
            const float4* wr4 = (const float4*)&w6[j * 32];
            const float4* hv = (const float4*)&sH0[(ssd * 9 + v) * 44];
            #pragma unroll
            for (int qq = 0; qq < 8; ++qq) {
                float4 w = wr4[qq], h = hv[qq];
                acc = fmaf(w.x, h.x, acc); acc = fmaf(w.y, h.y, acc);
                acc = fmaf(w.z, h.z, acc); acc = fmaf(w.w, h.w, acc);
            }
            sT1[idx] = acc > 15.f ? acc : log1pf(__expf(acc));
        }
    }
    __syncthreads();
    for (int idx = tid; idx < SB * 135; idx += NTH) {
        int ssd = idx / 135, rem = idx - ssd * 135;
        int v = rem / 15, f = rem - v * 15;
        if (ssd < nsamp) {
            float acc = b7[f];
            const float4* wr = (const float4*)&w7[f * 60];
            const float4* tv = (const float4*)&sT1[ssd * 540 + v * 60];
            #pragma unroll
            for (int qq = 0; qq < 15; ++qq) {
                float4 w = wr[qq], h = tv[qq];
                acc = fmaf(w.x, h.x, acc); acc = fmaf(w.y, h.y, acc);
                acc = fmaf(w.z, h.z, acc); acc = fmaf(w.w, h.w, acc);
            }
            sTF[idx] = fast_tanh(acc);
        }
    }
    __syncthreads();
    if (tid < SB && tid < nsamp) {
        const float* tf = &sTF[tid * 135];
        float sum = 0.f;
        for (int i = 0; i < 135; ++i) sum += tf[i];
        float mu = sum * (1.f / 135.f);
        float sq = 0.f;
        for (int i = 0; i < 135; ++i) { float d = tf[i] - mu; sq = fmaf(d, d, sq); }
        float sd = sqrtf(sq * (1.f / 134.f));  // ddof=1
        sST[tid * 2]     = mu;
        sST[tid * 2 + 1] = 1.f / fmaxf(sd, 1e-5f);
    }
    __syncthreads();
    const size_t encbase = (size_t)Bn * 288;
    for (int idx = tid; idx < SB * 135; idx += NTH) {
        int ssd = idx / 135, j = idx - ssd * 135;
        if (ssd < nsamp) {
            int qq = j / 15, pp = j - qq * 15;
            float val = (sTF[ssd * 135 + pp * 9 + qq] - sST[ssd * 2]) * sST[ssd * 2 + 1] * rev_w[j] + rev_b[j];
            out[encbase + (size_t)(b0 + ssd) * 135 + j] = val;
        }
    }
}

extern "C" void kernel_launch(void* const* d_in, const int* in_sizes, int n_in,
                              void* d_out, int out_size, void* d_ws, size_t ws_size,
                              hipStream_t stream) {
    const float* x    = (const float*)d_in[0];
    const float* bn_g = (const float*)d_in[1];
    const float* bn_b = (const float*)d_in[2];
    const float* bn_m = (const float*)d_in[3];
    const float* bn_v = (const float*)d_in[4];
    const float* wq2  = (const float*)d_in[5];
    const float* wk2  = (const float*)d_in[6];
    const float* wv2  = (const float*)d_in[7];
    const float* wo2  = (const float*)d_in[8];
    const float* bo2  = (const float*)d_in[9];
    const float* ln2g = (const float*)d_in[10];
    const float* ln2b = (const float*)d_in[11];
    const float* wq4  = (const float*)d_in[12];
    const float* wk4  = (const float*)d_in[13];
    const float* wv4  = (const float*)d_in[14];
    const float* wo4  = (const float*)d_in[15];
    const float* bo4  = (const float*)d_in[16];
    const float* ln4g = (const float*)d_in[17];
    const float* ln4b = (const float*)d_in[18];
    const float* w_ih = (const float*)d_in[19];
    const float* w_hh = (const float*)d_in[20];
    const float* b_ih = (const float*)d_in[21];
    const float* b_hh = (const float*)d_in[22];
    const float* cg_w = (const float*)d_in[23];
    const float* cg_uw= (const float*)d_in[24];
    const float* cg_ub= (const float*)d_in[25];
    const float* w6   = (const float*)d_in[26];
    const float* b6   = (const float*)d_in[27];
    const float* w7   = (const float*)d_in[28];
    const float* b7   = (const float*)d_in[29];
    const float* rev_w= (const float*)d_in[30];
    const float* rev_b= (const float*)d_in[31];

    int Bn = in_sizes[0] / 1080;
    int grid = (Bn + SB - 1) / SB;
    hipLaunchKernelGGL(se_kernel, dim3(grid), dim3(NTH), 0, stream,
                       x, bn_g, bn_b, bn_m, bn_v, wq2, wk2, wv2, wo2, bo2, ln2g, ln2b,
                       wq4, wk4, wv4, wo4, bo4, ln4g, ln4b,
                       w_ih, w_hh, b_ih, b_hh, cg_w, cg_uw, cg_ub,
                       w6, b6, w7, b7, rev_w, rev_b,
                       (float*)d_out, Bn);
}

// Round 5
// 1641.862 us; speedup vs baseline: 1.8954x; 1.7806x over previous
//
#include <hip/hip_runtime.h>
#include <math.h>

#define NTH 256
#define SB 4   // samples per block

typedef __attribute__((ext_vector_type(8))) short bf16x8;
typedef __attribute__((ext_vector_type(4))) float f32x4;

// v_rcp_f32 (~1 ulp) instead of IEEE divide (~16-20 cy of rcp+Newton fixups).
// Error ~1e-7 rel, ~4000x below the bf16 rounding already in the h-recurrence.
__device__ __forceinline__ float fast_sigmoid(float x) {
    return __builtin_amdgcn_rcpf(1.0f + __expf(-x));
}
__device__ __forceinline__ float fast_tanh(float x) {
    return fmaf(-2.0f, __builtin_amdgcn_rcpf(__expf(2.0f * x) + 1.0f), 1.0f);
}
__device__ __forceinline__ short f2bf(float x) {
    unsigned u = __float_as_uint(x);
    return (short)((u + 0x7FFFu + ((u >> 16) & 1u)) >> 16);   // RNE
}

// LDS layout (dwords) — 9108 dw = 36,432 B; 4 x 36,864 = 147,456 B = 144 KiB
// (tests the effective-LDS/CU hypothesis for a 4th resident block):
//  sU   @0      (4320)  [36 rows][120]; Phase D aliases sT1/sTF here
//  SCR  @4320   (4320)  A: S0..S3 | B: V[2][1080]+Y[2][1080] | C: sH0+sH1 (2x2112)
//  W    @8640   (468)   A-weights; Phase B overlays bo4/ln4g/ln4b here at B-start
extern "C" __global__ void __launch_bounds__(NTH, 3)
se_kernel(const float* __restrict__ x,
          const float* __restrict__ bn_g, const float* __restrict__ bn_b,
          const float* __restrict__ bn_m, const float* __restrict__ bn_v,
          const float* __restrict__ wq2, const float* __restrict__ wk2,
          const float* __restrict__ wv2, const float* __restrict__ wo2,
          const float* __restrict__ bo2, const float* __restrict__ ln2g,
          const float* __restrict__ ln2b,
          const float* __restrict__ wq4, const float* __restrict__ wk4,
          const float* __restrict__ wv4, const float* __restrict__ wo4,
          const float* __restrict__ bo4, const float* __restrict__ ln4g,
          const float* __restrict__ ln4b,
          const float* __restrict__ w_ih, const float* __restrict__ w_hh,
          const float* __restrict__ b_ih, const float* __restrict__ b_hh,
          const float* __restrict__ cg_w, const float* __restrict__ cg_uw,
          const float* __restrict__ cg_ub,
          const float* __restrict__ w6, const float* __restrict__ b6,
          const float* __restrict__ w7, const float* __restrict__ b7,
          const float* __restrict__ rev_w, const float* __restrict__ rev_b,
          float* __restrict__ out, int Bn)
{
    __shared__ __align__(16) float sm[9108];
    const int tid  = threadIdx.x;
    const int lane = tid & 63;
    const int wv   = tid >> 6;
    const int b0   = blockIdx.x * SB;
    const int nsamp = min(SB, Bn - b0);

    float* sU  = sm;            // 4320
    float* SCR = sm + 4320;     // 4320
    // Phase-A weights (dead after A):
    float* sWQ2 = sm + 8640; float* sWK2 = sm + 8724;
    float* sWV2 = sm + 8808; float* sWO2 = sm + 8892;
    float* sBO2 = sm + 8976; float* sLN2G = sm + 8988; float* sLN2B = sm + 9000;
    float* sKV = sm + 9012; float* sKS = sm + 9096;
    // Phase-B overlay of the same region (loaded at B-start):
    float* sBO4 = sm + 8640; float* sLN4G = sm + 8760; float* sLN4B = sm + 8880;
    float* sMU = sm + 9000; float* sRS = sm + 9020;
    // Phase-D:
    float* sST = sm + 9040;
    float* sH0 = SCR;           // 2112 : h plane 0 (final h lands here)
    float* sH1 = SCR + 2112;    // 2112 : h plane 1
    float* sT1 = sU;            // 2160 (Phase D alias; sU dead after C)
    float* sTF = sU + 2160;     // 540  (Phase D alias)

    // ---- Phase 0: stage Phase-A weights ----
    for (int i = tid; i < 81; i += NTH) {
        sWQ2[i] = wq2[i]; sWK2[i] = wk2[i]; sWV2[i] = wv2[i]; sWO2[i] = wo2[i];
    }
    if (tid < 9) { sBO2[tid] = bo2[tid]; sLN2G[tid] = ln2g[tid]; sLN2B[tid] = ln2b[tid]; }
    __syncthreads();

    // ---- Phase A: lin_attn_2 per sample -> u rows in sU (R0 verbatim) ----
    float* S0 = SCR; float* S1 = SCR + 1080; float* S2 = SCR + 2160; float* S3 = SCR + 3240;
    for (int ss = 0; ss < SB; ++ss) {
        if (ss < nsamp) {
            const int b = b0 + ss;
            for (int i = tid; i < 1080; i += NTH) {
                float xv = x[(size_t)b * 1080 + i];
                S0[i] = (xv - bn_m[i]) * rsqrtf(bn_v[i] + 1e-5f) * bn_g[i] + bn_b[i];
            }
            __syncthreads();
            for (int idx = tid; idx < 1080; idx += NTH) {
                int s = idx / 9, e = idx - s * 9;
                float aq = 0.f, ak = 0.f, av = 0.f;
                #pragma unroll
                for (int d = 0; d < 9; ++d) {
                    float xv = S0[s * 9 + d];
                    aq = fmaf(xv, sWQ2[e * 9 + d], aq);
                    ak = fmaf(xv, sWK2[e * 9 + d], ak);
                    av = fmaf(xv, sWV2[e * 9 + d], av);
                }
                S1[idx] = aq >= 0.f ? aq + 1.f : __expf(aq);
                S2[idx] = ak >= 0.f ? ak + 1.f : __expf(ak);
                S3[idx] = av;
            }
            __syncthreads();
            if (tid < 81) {
                int d = tid / 9, e = tid - d * 9;
                float acc = 0.f;
                for (int s = 0; s < 120; ++s) acc = fmaf(S2[s * 9 + d], S3[s * 9 + e], acc);
                sKV[tid] = acc;
            } else if (tid < 90) {
                int d = tid - 81;
                float acc = 0.f;
                for (int s = 0; s < 120; ++s) acc += S2[s * 9 + d];
                sKS[d] = acc;
            }
            __syncthreads();
            for (int idx = tid; idx < 1080; idx += NTH) {
                int s = idx / 9, e = idx - s * 9;
                float num = 0.f, den = 0.f;
                #pragma unroll
                for (int d = 0; d < 9; ++d) {
                    float qv = S1[s * 9 + d];
                    num = fmaf(qv, sKV[d * 9 + e], num);
                    den = fmaf(qv, sKS[d], den);
                }
                S0[idx] = num / fmaxf(den, 1e-6f);
            }
            __syncthreads();
            for (int idx = tid; idx < 1080; idx += NTH) {
                int s = idx / 9, f = idx - s * 9;
                float acc = sBO2[f] + S0[s * 9 + f];
                #pragma unroll
                for (int e = 0; e < 9; ++e) acc = fmaf(S0[s * 9 + e], sWO2[f * 9 + e], acc);
                S1[idx] = acc;
            }
            __syncthreads();
            if (tid < 120) {
                int s = tid;
                float sum = 0.f, sq = 0.f;
                #pragma unroll
                for (int f = 0; f < 9; ++f) { float v = S1[s * 9 + f]; sum += v; sq = fmaf(v, v, sq); }
                float mu = sum * (1.f / 9.f);
                float rs = rsqrtf(sq * (1.f / 9.f) - mu * mu + 1e-5f);
                #pragma unroll
                for (int f = 0; f < 9; ++f)
                    sU[(ss * 9 + f) * 120 + s] = (S1[s * 9 + f] - mu) * rs * sLN2G[f] + sLN2B[f];
            }
        }
        __syncthreads();
    }

    // ---- Phase B: lin_attn_4, o == V bit-exactly (R4-proven delete) ----
    // Overlay Phase-B params into the dead Phase-A weight region.
    for (int i = tid; i < 120; i += NTH) { sBO4[i] = bo4[i]; sLN4G[i] = ln4g[i]; sLN4B[i] = ln4b[i]; }
    // (visibility to other threads guaranteed by the V-pass/Y-pass barrier below)
    for (int p = 0; p < 2; ++p) {
        float* V0 = SCR;               // V[2][1080]
        float* Y0 = SCR + 2160;        // Y[2][1080]
        if (tid < 120) {               // V rows e0,e0+1 for sample sp of the pair
            int sp = tid / 60, ep = tid - sp * 60;
            int e0 = ep * 2;
            const float* uB = sU + (p * 2 + sp) * 1080;
            float acc[2][9];
            #pragma unroll
            for (int r = 0; r < 2; ++r)
                #pragma unroll
                for (int v = 0; v < 9; ++v) acc[r][v] = 0.f;
            const float* w0p = &wv4[e0 * 120];
            const float* w1p = &wv4[(e0 + 1) * 120];
            for (int dq = 0; dq < 30; ++dq) {
                float4 wA = *(const float4*)&w0p[dq * 4];
                float4 wB = *(const float4*)&w1p[dq * 4];
                #pragma unroll
                for (int v = 0; v < 9; ++v) {
                    float4 u = *(const float4*)&uB[v * 120 + dq * 4];
                    acc[0][v] = fmaf(wA.x, u.x, acc[0][v]); acc[0][v] = fmaf(wA.y, u.y, acc[0][v]);
                    acc[0][v] = fmaf(wA.z, u.z, acc[0][v]); acc[0][v] = fmaf(wA.w, u.w, acc[0][v]);
                    acc[1][v] = fmaf(wB.x, u.x, acc[1][v]); acc[1][v] = fmaf(wB.y, u.y, acc[1][v]);
                    acc[1][v] = fmaf(wB.z, u.z, acc[1][v]); acc[1][v] = fmaf(wB.w, u.w, acc[1][v]);
                }
            }
            float* dst = V0 + sp * 1080;
            #pragma unroll
            for (int v = 0; v < 9; ++v) {
                dst[v * 120 + e0]     = acc[0][v];
                dst[v * 120 + e0 + 1] = acc[1][v];
            }
        }
        __syncthreads();
        if (tid < 120) {               // Y rows e0,e0+1 (verbatim chain)
            int sp = tid / 60, ep = tid - sp * 60;
            int e0 = ep * 2;
            const float* vB = V0 + sp * 1080;
            float acc[2][9];
            #pragma unroll
            for (int r = 0; r < 2; ++r)
                #pragma unroll
                for (int v = 0; v < 9; ++v) acc[r][v] = 0.f;
            const float* w0p = &wo4[e0 * 120];
            const float* w1p = &wo4[(e0 + 1) * 120];
            for (int dq = 0; dq < 30; ++dq) {
                float4 wA = *(const float4*)&w0p[dq * 4];
                float4 wB = *(const float4*)&w1p[dq * 4];
                #pragma unroll
                for (int v = 0; v < 9; ++v) {
                    float4 u = *(const float4*)&vB[v * 120 + dq * 4];
                    acc[0][v] = fmaf(wA.x, u.x, acc[0][v]); acc[0][v] = fmaf(wA.y, u.y, acc[0][v]);
                    acc[0][v] = fmaf(wA.z, u.z, acc[0][v]); acc[0][v] = fmaf(wA.w, u.w, acc[0][v]);
                    acc[1][v] = fmaf(wB.x, u.x, acc[1][v]); acc[1][v] = fmaf(wB.y, u.y, acc[1][v]);
                    acc[1][v] = fmaf(wB.z, u.z, acc[1][v]); acc[1][v] = fmaf(wB.w, u.w, acc[1][v]);
                }
            }
            float* Y = Y0 + sp * 1080;
            #pragma unroll
            for (int v = 0; v < 9; ++v) {
                float o0 = vB[v * 120 + e0], o1 = vB[v * 120 + e0 + 1];
                Y[v * 120 + e0]     = acc[0][v] + sBO4[e0]     + o0;
                Y[v * 120 + e0 + 1] = acc[1][v] + sBO4[e0 + 1] + o1;
            }
        }
        __syncthreads();
        if (tid < 18) {                // LN stats (verbatim chain)
            int sp = tid / 9, v = tid - sp * 9;
            const float* Y = Y0 + sp * 1080 + v * 120;
            float sum = 0.f, sq = 0.f;
            for (int e = 0; e < 120; ++e) { float t = Y[e]; sum += t; sq = fmaf(t, t, sq); }
            float mu = sum * (1.f / 120.f);
            sMU[tid] = mu;
            sRS[tid] = rsqrtf(sq * (1.f / 120.f) - mu * mu + 1e-5f);
        }
        __syncthreads();
        for (int idx = tid; idx < 540; idx += NTH) {   // LN apply (verbatim chain)
            int sp = idx / 270, off = idx - sp * 270;
            int v = off / 30, qq = off - v * 30;
            const float* Y = Y0 + sp * 1080;
            float4 y = *(const float4*)&Y[v * 120 + qq * 4];
            float4 g = *(const float4*)&sLN4G[qq * 4];
            float4 bb = *(const float4*)&sLN4B[qq * 4];
            float mu = sMU[sp * 9 + v], rs = sRS[sp * 9 + v];
            float4 o;
            o.x = (y.x - mu) * rs * g.x + bb.x;
            o.y = (y.y - mu) * rs * g.y + bb.y;
            o.z = (y.z - mu) * rs * g.z + bb.z;
            o.w = (y.w - mu) * rs * g.w + bb.w;
            *(float4*)&sU[((p * 2 + sp) * 9 + v) * 120 + qq * 4] = o;
        }
        __syncthreads();
    }

    // ---- Phase C: CGLSTM via MFMA — BARRIER-FREE steps.
    //      Wave wv writes only h rows [16wv,16wv+16) (grow[r] = wv*16 + probe
    //      row, probe row in [0,16)) and reads only row wv*16+c of the same
    //      stripe -> zero cross-wave data flow. Within a wave, DS ops execute
    //      in program order, and the dbuf planes make step-local read/write
    //      sets disjoint. One barrier after the loop publishes final h.
    for (int i = tid; i < 2112; i += NTH) sH0[i] = 0.f;   // h0 = 0 (plane 0)
    __syncthreads();

    const int c = lane & 15, q = lane >> 4;
    bf16x8 bfr[8]; float wxv[8], bsv[8];
    int grow[4] = {0, 0, 0, 0}; int pcol = 0;
    if (wv < 3) {
        // Probe 1: A(m,0)=m, B(0,n)=1  -> D slot value = its ROW
        // Probe 2: A(m,0)=1, B(0,n)=n  -> D slot value = its COLUMN
        bf16x8 pa, pb, pa2, pb2;
        #pragma unroll
        for (int j = 0; j < 8; ++j) { pa[j] = 0; pb[j] = 0; pa2[j] = 0; pb2[j] = 0; }
        if (q == 0) {
            pa[0]  = f2bf((float)c); pb[0]  = f2bf(1.0f);
            pa2[0] = f2bf(1.0f);     pb2[0] = f2bf((float)c);
        }
        f32x4 zc; zc[0] = zc[1] = zc[2] = zc[3] = 0.f;
        f32x4 prr = __builtin_amdgcn_mfma_f32_16x16x32_bf16(pa,  pb,  zc, 0, 0, 0);
        f32x4 pcc = __builtin_amdgcn_mfma_f32_16x16x32_bf16(pa2, pb2, zc, 0, 0, 0);
        #pragma unroll
        for (int r = 0; r < 4; ++r) grow[r] = wv * 16 + (int)(prr[r] + 0.5f);
        pcol = (int)(pcc[0] + 0.5f);

        #pragma unroll
        for (int T = 0; T < 8; ++T) {
            int gate = T >> 1, kk = ((T & 1) << 4) + pcol;
            const float* wr; float wx, bs;
            if (gate < 3) {
                int n = gate * 32 + kk;
                wr = &w_hh[n * 32]; wx = w_ih[n]; bs = b_ih[n] + b_hh[n];
            } else {
                wr = &cg_uw[kk * 32]; wx = cg_w[kk]; bs = cg_ub[kk];
            }
            bf16x8 tv;
            #pragma unroll
            for (int j = 0; j < 8; ++j) tv[j] = f2bf(wr[q * 8 + j]);
            bfr[T] = tv; wxv[T] = wx; bsv[T] = bs;
        }
    }
    float cst[8];
    #pragma unroll
    for (int i = 0; i < 8; ++i) cst[i] = 0.f;
    const int live9 = nsamp * 9;
    const float* ar0 = &sH0[(wv * 16 + c) * 44 + q * 8];
    const float* ar1 = &sH1[(wv * 16 + c) * 44 + q * 8];

// One LSTM step, no barrier: read plane RP, write plane WPL (disjoint).
#define LSTM_STEP(RP, WPL, XARR)                                               \
    if (wv < 3) {                                                              \
        float4 hA = *(const float4*)(RP);                                      \
        float4 hB = *(const float4*)((RP) + 4);                                \
        bf16x8 af;                                                             \
        af[0] = f2bf(hA.x); af[1] = f2bf(hA.y);                                \
        af[2] = f2bf(hA.z); af[3] = f2bf(hA.w);                                \
        af[4] = f2bf(hB.x); af[5] = f2bf(hB.y);                                \
        af[6] = f2bf(hB.z); af[7] = f2bf(hB.w);                                \
        f32x4 acc[8];                                                          \
        _Pragma("unroll")                                                      \
        for (int T = 0; T < 8; ++T) {                                          \
            f32x4 ci;                                                          \
            _Pragma("unroll")                                                  \
            for (int r = 0; r < 4; ++r) ci[r] = fmaf(wxv[T], XARR[r], bsv[T]); \
            acc[T] = __builtin_amdgcn_mfma_f32_16x16x32_bf16(af, bfr[T], ci, 0, 0, 0); \
        }                                                                      \
        _Pragma("unroll")                                                      \
        for (int kh = 0; kh < 2; ++kh) {                                       \
            _Pragma("unroll")                                                  \
            for (int r = 0; r < 4; ++r) {                                      \
                float si  = fast_sigmoid(acc[kh][r]);                          \
                float sf  = fast_sigmoid(acc[2 + kh][r]);                      \
                float tg  = fast_tanh(acc[4 + kh][r]);                         \
                float sgc = fast_sigmoid(acc[6 + kh][r]);                      \
                float cn = fmaf(sf, cst[kh * 4 + r], si * tg);                 \
                cst[kh * 4 + r] = cn;                                          \
                (WPL)[grow[r] * 44 + (kh << 4) + pcol] = sgc * fast_tanh(cn);  \
            }                                                                  \
        }                                                                      \
    }

    for (int t = 0; t < 120; t += 2) {
        float xa[4], xb[4];
        if (wv < 3) {
            #pragma unroll
            for (int r = 0; r < 4; ++r) {
                float2 xv;
                if (grow[r] < live9) xv = *(const float2*)&sU[grow[r] * 120 + t];
                else { xv.x = 0.f; xv.y = 0.f; }
                xa[r] = xv.x; xb[r] = xv.y;
            }
        }
        LSTM_STEP(ar0, sH1, xa)     // even step: plane0 -> plane1
        LSTM_STEP(ar1, sH0, xb)     // odd step:  plane1 -> plane0
    }
    __syncthreads();   // publish final h (plane 0) to all waves

    // cglstm_out (output 0) straight from the LDS h-plane
    for (int idx = tid; idx < SB * 288; idx += NTH) {
        int ssd = idx / 288, r = idx - ssd * 288;
        if (ssd < nsamp) {
            int v = r >> 5, k = r & 31;
            out[(size_t)(b0 + ssd) * 288 + r] = sH0[(ssd * 9 + v) * 44 + k];
        }
    }

    // ---- Phase D: conv6(softplus) -> conv7(tanh) -> RevIN ----
    for (int idx = tid; idx < SB * 540; idx += NTH) {
        int ssd = idx / 540, rem = idx - ssd * 540;
        int v = rem / 60, j = rem - v * 60;
        if (ssd < nsamp) {
            float acc = b6[j];
            const float4* wr4 = (const float4*)&w6[j * 32];
            const float4* hv = (const float4*)&sH0[(ssd * 9 + v) * 44];
            #pragma unroll
            for (int qq = 0; qq < 8; ++qq) {
                float4 w = wr4[qq], h = hv[qq];
                acc = fmaf(w.x, h.x, acc); acc = fmaf(w.y, h.y, acc);
                acc = fmaf(w.z, h.z, acc); acc = fmaf(w.w, h.w, acc);
            }
            sT1[idx] = acc > 15.f ? acc : log1pf(__expf(acc));
        }
    }
    __syncthreads();
    for (int idx = tid; idx < SB * 135; idx += NTH) {
        int ssd = idx / 135, rem = idx - ssd * 135;
        int v = rem / 15, f = rem - v * 15;
        if (ssd < nsamp) {
            float acc = b7[f];
            const float4* wr = (const float4*)&w7[f * 60];
            const float4* tv = (const float4*)&sT1[ssd * 540 + v * 60];
            #pragma unroll
            for (int qq = 0; qq < 15; ++qq) {
                float4 w = wr[qq], h = tv[qq];
                acc = fmaf(w.x, h.x, acc); acc = fmaf(w.y, h.y, acc);
                acc = fmaf(w.z, h.z, acc); acc = fmaf(w.w, h.w, acc);
            }
            sTF[idx] = fast_tanh(acc);
        }
    }
    __syncthreads();
    if (tid < SB && tid < nsamp) {
        const float* tf = &sTF[tid * 135];
        float sum = 0.f;
        for (int i = 0; i < 135; ++i) sum += tf[i];
        float mu = sum * (1.f / 135.f);
        float sq = 0.f;
        for (int i = 0; i < 135; ++i) { float d = tf[i] - mu; sq = fmaf(d, d, sq); }
        float sd = sqrtf(sq * (1.f / 134.f));  // ddof=1
        sST[tid * 2]     = mu;
        sST[tid * 2 + 1] = 1.f / fmaxf(sd, 1e-5f);
    }
    __syncthreads();
    const size_t encbase = (size_t)Bn * 288;
    for (int idx = tid; idx < SB * 135; idx += NTH) {
        int ssd = idx / 135, j = idx - ssd * 135;
        if (ssd < nsamp) {
            int qq = j / 15, pp = j - qq * 15;
            float val = (sTF[ssd * 135 + pp * 9 + qq] - sST[ssd * 2]) * sST[ssd * 2 + 1] * rev_w[j] + rev_b[j];
            out[encbase + (size_t)(b0 + ssd) * 135 + j] = val;
        }
    }
}

extern "C" void kernel_launch(void* const* d_in, const int* in_sizes, int n_in,
                              void* d_out, int out_size, void* d_ws, size_t ws_size,
                              hipStream_t stream) {
    const float* x    = (const float*)d_in[0];
    const float* bn_g = (const float*)d_in[1];
    const float* bn_b = (const float*)d_in[2];
    const float* bn_m = (const float*)d_in[3];
    const float* bn_v = (const float*)d_in[4];
    const float* wq2  = (const float*)d_in[5];
    const float* wk2  = (const float*)d_in[6];
    const float* wv2  = (const float*)d_in[7];
    const float* wo2  = (const float*)d_in[8];
    const float* bo2  = (const float*)d_in[9];
    const float* ln2g = (const float*)d_in[10];
    const float* ln2b = (const float*)d_in[11];
    const float* wq4  = (const float*)d_in[12];
    const float* wk4  = (const float*)d_in[13];
    const float* wv4  = (const float*)d_in[14];
    const float* wo4  = (const float*)d_in[15];
    const float* bo4  = (const float*)d_in[16];
    const float* ln4g = (const float*)d_in[17];
    const float* ln4b = (const float*)d_in[18];
    const float* w_ih = (const float*)d_in[19];
    const float* w_hh = (const float*)d_in[20];
    const float* b_ih = (const float*)d_in[21];
    const float* b_hh = (const float*)d_in[22];
    const float* cg_w = (const float*)d_in[23];
    const float* cg_uw= (const float*)d_in[24];
    const float* cg_ub= (const float*)d_in[25];
    const float* w6   = (const float*)d_in[26];
    const float* b6   = (const float*)d_in[27];
    const float* w7   = (const float*)d_in[28];
    const float* b7   = (const float*)d_in[29];
    const float* rev_w= (const float*)d_in[30];
    const float* rev_b= (const float*)d_in[31];

    int Bn = in_sizes[0] / 1080;
    int grid = (Bn + SB - 1) / SB;
    hipLaunchKernelGGL(se_kernel, dim3(grid), dim3(NTH), 0, stream,
                       x, bn_g, bn_b, bn_m, bn_v, wq2, wk2, wv2, wo2, bo2, ln2g, ln2b,
                       wq4, wk4, wv4, wo4, bo4, ln4g, ln4b,
                       w_ih, w_hh, b_ih, b_hh, cg_w, cg_uw, cg_ub,
                       w6, b6, w7, b7, rev_w, rev_b,
                       (float*)d_out, Bn);
}

// Round 6
// 1523.519 us; speedup vs baseline: 2.0426x; 1.0777x over previous
//
#include <hip/hip_runtime.h>
#include <math.h>

#define NTH 256
#define SB 7   // samples per block: 63 live h-rows of 64 (4 waves x 16)

typedef __attribute__((ext_vector_type(8))) short bf16x8;
typedef __attribute__((ext_vector_type(4))) float f32x4;

// v_rcp_f32 (~1 ulp) instead of IEEE divide (R5-proven).
__device__ __forceinline__ float fast_sigmoid(float x) {
    return __builtin_amdgcn_rcpf(1.0f + __expf(-x));
}
__device__ __forceinline__ float fast_tanh(float x) {
    return fmaf(-2.0f, __builtin_amdgcn_rcpf(__expf(2.0f * x) + 1.0f), 1.0f);
}
__device__ __forceinline__ short f2bf(float x) {
    unsigned u = __float_as_uint(x);
    return (short)((u + 0x7FFFu + ((u >> 16) & 1u)) >> 16);   // RNE
}

// LDS layout (dwords) — 13,552 dw = 54,208 B -> 54,272 B alloc; 3/CU = 162,816 <= 160 KiB.
//  sU   @0      (7560)  [63 rows][120]; Phase D aliases sT1(3780)/sTF(945) here
//  SCR  @7560   (5632)  A: S0..S3(4320)+sKV/sKS | B: V(2160)+Y(2160)+sMU/sRS | C: sH0+sH1 (2x2816)
//  W    @13192  (360)   A: wq2/wk2/wv2/wo2/bo2/ln2g/ln2b | B overlay: bo4/ln4g/ln4b
extern "C" __global__ void __launch_bounds__(NTH, 3)
se_kernel(const float* __restrict__ x,
          const float* __restrict__ bn_g, const float* __restrict__ bn_b,
          const float* __restrict__ bn_m, const float* __restrict__ bn_v,
          const float* __restrict__ wq2, const float* __restrict__ wk2,
          const float* __restrict__ wv2, const float* __restrict__ wo2,
          const float* __restrict__ bo2, const float* __restrict__ ln2g,
          const float* __restrict__ ln2b,
          const float* __restrict__ wq4, const float* __restrict__ wk4,
          const float* __restrict__ wv4, const float* __restrict__ wo4,
          const float* __restrict__ bo4, const float* __restrict__ ln4g,
          const float* __restrict__ ln4b,
          const float* __restrict__ w_ih, const float* __restrict__ w_hh,
          const float* __restrict__ b_ih, const float* __restrict__ b_hh,
          const float* __restrict__ cg_w, const float* __restrict__ cg_uw,
          const float* __restrict__ cg_ub,
          const float* __restrict__ w6, const float* __restrict__ b6,
          const float* __restrict__ w7, const float* __restrict__ b7,
          const float* __restrict__ rev_w, const float* __restrict__ rev_b,
          float* __restrict__ out, int Bn)
{
    __shared__ __align__(16) float sm[13552];
    const int tid  = threadIdx.x;
    const int lane = tid & 63;
    const int wv   = tid >> 6;
    const int b0   = blockIdx.x * SB;
    const int nsamp = min(SB, Bn - b0);

    float* sU  = sm;            // 7560
    float* SCR = sm + 7560;     // 5632
    // Phase-A weights (dead after A):
    float* sWQ2 = sm + 13192; float* sWK2 = sm + 13273;
    float* sWV2 = sm + 13354; float* sWO2 = sm + 13435;
    float* sBO2 = sm + 13516; float* sLN2G = sm + 13525; float* sLN2B = sm + 13534;
    float* sKV = sm + 11880;  float* sKS = sm + 11961;   // SCR+4320.. (free during A)
    // Phase-B overlay (loaded at B-start, over dead A weights):
    float* sBO4 = sm + 13192; float* sLN4G = sm + 13312; float* sLN4B = sm + 13432;
    float* sMU = sm + 11880;  float* sRS = sm + 11900;   // SCR+4320.. (V/Y use 0..4320)
    // Phase-D (inside dead sH1):
    float* sST = sm + 11920;
    float* sH0 = SCR;           // 2816 : h plane 0 [64 rows][44] (final h here)
    float* sH1 = SCR + 2816;    // 2816 : h plane 1
    float* sT1 = sU;            // 3780 (Phase D alias; sU dead after C)
    float* sTF = sU + 3780;     // 945  (Phase D alias)

    // ---- Phase 0: stage Phase-A weights ----
    for (int i = tid; i < 81; i += NTH) {
        sWQ2[i] = wq2[i]; sWK2[i] = wk2[i]; sWV2[i] = wv2[i]; sWO2[i] = wo2[i];
    }
    if (tid < 9) { sBO2[tid] = bo2[tid]; sLN2G[tid] = ln2g[tid]; sLN2B[tid] = ln2b[tid]; }
    __syncthreads();

    // ---- Phase A: lin_attn_2 per sample -> u rows in sU (R0 verbatim chains) ----
    float* S0 = SCR; float* S1 = SCR + 1080; float* S2 = SCR + 2160; float* S3 = SCR + 3240;
    for (int ss = 0; ss < SB; ++ss) {
        if (ss < nsamp) {
            const int b = b0 + ss;
            for (int i = tid; i < 1080; i += NTH) {
                float xv = x[(size_t)b * 1080 + i];
                S0[i] = (xv - bn_m[i]) * rsqrtf(bn_v[i] + 1e-5f) * bn_g[i] + bn_b[i];
            }
            __syncthreads();
            for (int idx = tid; idx < 1080; idx += NTH) {
                int s = idx / 9, e = idx - s * 9;
                float aq = 0.f, ak = 0.f, av = 0.f;
                #pragma unroll
                for (int d = 0; d < 9; ++d) {
                    float xv = S0[s * 9 + d];
                    aq = fmaf(xv, sWQ2[e * 9 + d], aq);
                    ak = fmaf(xv, sWK2[e * 9 + d], ak);
                    av = fmaf(xv, sWV2[e * 9 + d], av);
                }
                S1[idx] = aq >= 0.f ? aq + 1.f : __expf(aq);
                S2[idx] = ak >= 0.f ? ak + 1.f : __expf(ak);
                S3[idx] = av;
            }
            __syncthreads();
            if (tid < 81) {
                int d = tid / 9, e = tid - d * 9;
                float acc = 0.f;
                for (int s = 0; s < 120; ++s) acc = fmaf(S2[s * 9 + d], S3[s * 9 + e], acc);
                sKV[tid] = acc;
            } else if (tid < 90) {
                int d = tid - 81;
                float acc = 0.f;
                for (int s = 0; s < 120; ++s) acc += S2[s * 9 + d];
                sKS[d] = acc;
            }
            __syncthreads();
            for (int idx = tid; idx < 1080; idx += NTH) {
                int s = idx / 9, e = idx - s * 9;
                float num = 0.f, den = 0.f;
                #pragma unroll
                for (int d = 0; d < 9; ++d) {
                    float qv = S1[s * 9 + d];
                    num = fmaf(qv, sKV[d * 9 + e], num);
                    den = fmaf(qv, sKS[d], den);
                }
                S0[idx] = num / fmaxf(den, 1e-6f);
            }
            __syncthreads();
            for (int idx = tid; idx < 1080; idx += NTH) {
                int s = idx / 9, f = idx - s * 9;
                float acc = sBO2[f] + S0[s * 9 + f];
                #pragma unroll
                for (int e = 0; e < 9; ++e) acc = fmaf(S0[s * 9 + e], sWO2[f * 9 + e], acc);
                S1[idx] = acc;
            }
            __syncthreads();
            if (tid < 120) {
                int s = tid;
                float sum = 0.f, sq = 0.f;
                #pragma unroll
                for (int f = 0; f < 9; ++f) { float v = S1[s * 9 + f]; sum += v; sq = fmaf(v, v, sq); }
                float mu = sum * (1.f / 9.f);
                float rs = rsqrtf(sq * (1.f / 9.f) - mu * mu + 1e-5f);
                #pragma unroll
                for (int f = 0; f < 9; ++f)
                    sU[(ss * 9 + f) * 120 + s] = (S1[s * 9 + f] - mu) * rs * sLN2G[f] + sLN2B[f];
            }
        }
        __syncthreads();
    }

    // ---- Phase B: lin_attn_4, o == V bit-exactly (R4-proven). 240 threads,
    //      1 row/thread, 4 pair-iterations over 7 samples. Per-row fmaf chains
    //      keep the proven order (dq, then v, then x/y/z/w) -> bit-identical.
    //      Dead-sample (smp >= nsamp) garbage stays in dead LDS rows.
    for (int i = tid; i < 120; i += NTH) { sBO4[i] = bo4[i]; sLN4G[i] = ln4g[i]; sLN4B[i] = ln4b[i]; }
    for (int p = 0; p < 4; ++p) {
        float* V0 = SCR;               // V[2][1080]
        float* Y0 = SCR + 2160;        // Y[2][1080]
        const int sp = tid / 120, erow = tid - sp * 120;
        const int smp = p * 2 + sp;
        const bool act = (tid < 240) && (smp < SB);
        if (act) {   // V row erow for all 9 vars of sample smp
            const float* uB = sU + smp * 1080;
            float acc[9];
            #pragma unroll
            for (int v = 0; v < 9; ++v) acc[v] = 0.f;
            const float* w0p = &wv4[erow * 120];
            for (int dq = 0; dq < 30; ++dq) {
                float4 wA = *(const float4*)&w0p[dq * 4];
                #pragma unroll
                for (int v = 0; v < 9; ++v) {
                    float4 u = *(const float4*)&uB[v * 120 + dq * 4];
                    acc[v] = fmaf(wA.x, u.x, acc[v]); acc[v] = fmaf(wA.y, u.y, acc[v]);
                    acc[v] = fmaf(wA.z, u.z, acc[v]); acc[v] = fmaf(wA.w, u.w, acc[v]);
                }
            }
            float* dst = V0 + sp * 1080;
            #pragma unroll
            for (int v = 0; v < 9; ++v) dst[v * 120 + erow] = acc[v];
        }
        __syncthreads();
        if (act) {   // Y row erow (wo4 pass + residual, proven associativity)
            const float* vB = V0 + sp * 1080;
            float acc[9];
            #pragma unroll
            for (int v = 0; v < 9; ++v) acc[v] = 0.f;
            const float* w0p = &wo4[erow * 120];
            for (int dq = 0; dq < 30; ++dq) {
                float4 wA = *(const float4*)&w0p[dq * 4];
                #pragma unroll
                for (int v = 0; v < 9; ++v) {
                    float4 u = *(const float4*)&vB[v * 120 + dq * 4];
                    acc[v] = fmaf(wA.x, u.x, acc[v]); acc[v] = fmaf(wA.y, u.y, acc[v]);
                    acc[v] = fmaf(wA.z, u.z, acc[v]); acc[v] = fmaf(wA.w, u.w, acc[v]);
                }
            }
            float* Y = Y0 + sp * 1080;
            #pragma unroll
            for (int v = 0; v < 9; ++v)
                Y[v * 120 + erow] = acc[v] + sBO4[erow] + vB[v * 120 + erow];
        }
        __syncthreads();
        if (tid < 18 && (p * 2 + tid / 9) < SB) {   // LN stats (verbatim chain)
            int sp2 = tid / 9, v = tid - sp2 * 9;
            const float* Y = Y0 + sp2 * 1080 + v * 120;
            float sum = 0.f, sq = 0.f;
            for (int e = 0; e < 120; ++e) { float t = Y[e]; sum += t; sq = fmaf(t, t, sq); }
            float mu = sum * (1.f / 120.f);
            sMU[tid] = mu;
            sRS[tid] = rsqrtf(sq * (1.f / 120.f) - mu * mu + 1e-5f);
        }
        __syncthreads();
        for (int idx = tid; idx < 540; idx += NTH) {   // LN apply (verbatim chain)
            int sp2 = idx / 270, off = idx - sp2 * 270;
            int smp2 = p * 2 + sp2;
            int v = off / 30, qq = off - v * 30;
            if (smp2 < SB) {
                const float* Y = Y0 + sp2 * 1080;
                float4 y = *(const float4*)&Y[v * 120 + qq * 4];
                float4 g = *(const float4*)&sLN4G[qq * 4];
                float4 bb = *(const float4*)&sLN4B[qq * 4];
                float mu = sMU[sp2 * 9 + v], rs = sRS[sp2 * 9 + v];
                float4 o;
                o.x = (y.x - mu) * rs * g.x + bb.x;
                o.y = (y.y - mu) * rs * g.y + bb.y;
                o.z = (y.z - mu) * rs * g.z + bb.z;
                o.w = (y.w - mu) * rs * g.w + bb.w;
                *(float4*)&sU[(smp2 * 9 + v) * 120 + qq * 4] = o;
            }
        }
        __syncthreads();
    }

    // ---- Phase C: CGLSTM via MFMA — 4 waves x 16 rows, barrier-free steps.
    //      Wave wv owns h rows [16wv,16wv+16) in BOTH planes (reads+writes),
    //      dbuf planes keep step-local read/write sets disjoint.
    for (int i = tid; i < 2816; i += NTH) sH0[i] = 0.f;   // h0 = 0 (plane 0)
    __syncthreads();

    const int c = lane & 15, q = lane >> 4;
    bf16x8 bfr[8]; float wxv[8], bsv[8];
    int grow[4]; int pcol;
    {
        // Probe 1: A(m,0)=m, B(0,n)=1  -> D slot value = its ROW
        // Probe 2: A(m,0)=1, B(0,n)=n  -> D slot value = its COLUMN
        bf16x8 pa, pb, pa2, pb2;
        #pragma unroll
        for (int j = 0; j < 8; ++j) { pa[j] = 0; pb[j] = 0; pa2[j] = 0; pb2[j] = 0; }
        if (q == 0) {
            pa[0]  = f2bf((float)c); pb[0]  = f2bf(1.0f);
            pa2[0] = f2bf(1.0f);     pb2[0] = f2bf((float)c);
        }
        f32x4 zc; zc[0] = zc[1] = zc[2] = zc[3] = 0.f;
        f32x4 prr = __builtin_amdgcn_mfma_f32_16x16x32_bf16(pa,  pb,  zc, 0, 0, 0);
        f32x4 pcc = __builtin_amdgcn_mfma_f32_16x16x32_bf16(pa2, pb2, zc, 0, 0, 0);
        #pragma unroll
        for (int r = 0; r < 4; ++r) grow[r] = wv * 16 + (int)(prr[r] + 0.5f);
        pcol = (int)(pcc[0] + 0.5f);

        #pragma unroll
        for (int T = 0; T < 8; ++T) {
            int gate = T >> 1, kk = ((T & 1) << 4) + pcol;
            const float* wr; float wx, bs;
            if (gate < 3) {
                int n = gate * 32 + kk;
                wr = &w_hh[n * 32]; wx = w_ih[n]; bs = b_ih[n] + b_hh[n];
            } else {
                wr = &cg_uw[kk * 32]; wx = cg_w[kk]; bs = cg_ub[kk];
            }
            bf16x8 tv;
            #pragma unroll
            for (int j = 0; j < 8; ++j) tv[j] = f2bf(wr[q * 8 + j]);
            bfr[T] = tv; wxv[T] = wx; bsv[T] = bs;
        }
    }
    float cst[8];
    #pragma unroll
    for (int i = 0; i < 8; ++i) cst[i] = 0.f;
    const int live9 = nsamp * 9;
    const float* ar0 = &sH0[(wv * 16 + c) * 44 + q * 8];
    const float* ar1 = &sH1[(wv * 16 + c) * 44 + q * 8];

// One LSTM step, no barrier: read plane RP, write plane WPL (disjoint).
#define LSTM_STEP(RP, WPL, XARR)                                               \
    {                                                                          \
        float4 hA = *(const float4*)(RP);                                      \
        float4 hB = *(const float4*)((RP) + 4);                                \
        bf16x8 af;                                                             \
        af[0] = f2bf(hA.x); af[1] = f2bf(hA.y);                                \
        af[2] = f2bf(hA.z); af[3] = f2bf(hA.w);                                \
        af[4] = f2bf(hB.x); af[5] = f2bf(hB.y);                                \
        af[6] = f2bf(hB.z); af[7] = f2bf(hB.w);                                \
        f32x4 acc[8];                                                          \
        _Pragma("unroll")                                                      \
        for (int T = 0; T < 8; ++T) {                                          \
            f32x4 ci;                                                          \
            _Pragma("unroll")                                                  \
            for (int r = 0; r < 4; ++r) ci[r] = fmaf(wxv[T], XARR[r], bsv[T]); \
            acc[T] = __builtin_amdgcn_mfma_f32_16x16x32_bf16(af, bfr[T], ci, 0, 0, 0); \
        }                                                                      \
        _Pragma("unroll")                                                      \
        for (int kh = 0; kh < 2; ++kh) {                                       \
            _Pragma("unroll")                                                  \
            for (int r = 0; r < 4; ++r) {                                      \
                float si  = fast_sigmoid(acc[kh][r]);                          \
                float sf  = fast_sigmoid(acc[2 + kh][r]);                      \
                float tg  = fast_tanh(acc[4 + kh][r]);                         \
                float sgc = fast_sigmoid(acc[6 + kh][r]);                      \
                float cn = fmaf(sf, cst[kh * 4 + r], si * tg);                 \
                cst[kh * 4 + r] = cn;                                          \
                (WPL)[grow[r] * 44 + (kh << 4) + pcol] = sgc * fast_tanh(cn);  \
            }                                                                  \
        }                                                                      \
    }

    for (int t = 0; t < 120; t += 2) {
        float xa[4], xb[4];
        #pragma unroll
        for (int r = 0; r < 4; ++r) {
            float2 xv;
            if (grow[r] < live9) xv = *(const float2*)&sU[grow[r] * 120 + t];
            else { xv.x = 0.f; xv.y = 0.f; }
            xa[r] = xv.x; xb[r] = xv.y;
        }
        LSTM_STEP(ar0, sH1, xa)     // even step: plane0 -> plane1
        LSTM_STEP(ar1, sH0, xb)     // odd step:  plane1 -> plane0
    }
    __syncthreads();   // publish final h (plane 0) to all waves

    // cglstm_out (output 0) straight from the LDS h-plane
    for (int idx = tid; idx < SB * 288; idx += NTH) {
        int ssd = idx / 288, r = idx - ssd * 288;
        if (ssd < nsamp) {
            int v = r >> 5, k = r & 31;
            out[(size_t)(b0 + ssd) * 288 + r] = sH0[(ssd * 9 + v) * 44 + k];
        }
    }

    // ---- Phase D: conv6(softplus) -> conv7(tanh) -> RevIN ----
    for (int idx = tid; idx < SB * 540; idx += NTH) {
        int ssd = idx / 540, rem = idx - ssd * 540;
        int v = rem / 60, j = rem - v * 60;
        if (ssd < nsamp) {
            float acc = b6[j];
            const float4* wr4 = (const float4*)&w6[j * 32];
            const float4* hv = (const float4*)&sH0[(ssd * 9 + v) * 44];
            #pragma unroll
            for (int qq = 0; qq < 8; ++qq) {
                float4 w = wr4[qq], h = hv[qq];
                acc = fmaf(w.x, h.x, acc); acc = fmaf(w.y, h.y, acc);
                acc = fmaf(w.z, h.z, acc); acc = fmaf(w.w, h.w, acc);
            }
            sT1[idx] = acc > 15.f ? acc : log1pf(__expf(acc));
        }
    }
    __syncthreads();
    for (int idx = tid; idx < SB * 135; idx += NTH) {
        int ssd = idx / 135, rem = idx - ssd * 135;
        int v = rem / 15, f = rem - v * 15;
        if (ssd < nsamp) {
            float acc = b7[f];
            const float4* wr = (const float4*)&w7[f * 60];
            const float4* tv = (const float4*)&sT1[ssd * 540 + v * 60];
            #pragma unroll
            for (int qq = 0; qq < 15; ++qq) {
                float4 w = wr[qq], h = tv[qq];
                acc = fmaf(w.x, h.x, acc); acc = fmaf(w.y, h.y, acc);
                acc = fmaf(w.z, h.z, acc); acc = fmaf(w.w, h.w, acc);
            }
            sTF[idx] = fast_tanh(acc);
        }
    }
    __syncthreads();
    if (tid < SB && tid < nsamp) {
        const float* tf = &sTF[tid * 135];
        float sum = 0.f;
        for (int i = 0; i < 135; ++i) sum += tf[i];
        float mu = sum * (1.f / 135.f);
        float sq = 0.f;
        for (int i = 0; i < 135; ++i) { float d = tf[i] - mu; sq = fmaf(d, d, sq); }
        float sd = sqrtf(sq * (1.f / 134.f));  // ddof=1
        sST[tid * 2]     = mu;
        sST[tid * 2 + 1] = 1.f / fmaxf(sd, 1e-5f);
    }
    __syncthreads();
    const size_t encbase = (size_t)Bn * 288;
    for (int idx = tid; idx < SB * 135; idx += NTH) {
        int ssd = idx / 135, j = idx - ssd * 135;
        if (ssd < nsamp) {
            int qq = j / 15, pp = j - qq * 15;
            float val = (sTF[ssd * 135 + pp * 9 + qq] - sST[ssd * 2]) * sST[ssd * 2 + 1] * rev_w[j] + rev_b[j];
            out[encbase + (size_t)(b0 + ssd) * 135 + j] = val;
        }
    }
}

extern "C" void kernel_launch(void* const* d_in, const int* in_sizes, int n_in,
                              void* d_out, int out_size, void* d_ws, size_t ws_size,
                              hipStream_t stream) {
    const float* x    = (const float*)d_in[0];
    const float* bn_g = (const float*)d_in[1];
    const float* bn_b = (const float*)d_in[2];
    const float* bn_m = (const float*)d_in[3];
    const float* bn_v = (const float*)d_in[4];
    const float* wq2  = (const float*)d_in[5];
    const float* wk2  = (const float*)d_in[6];
    const float* wv2  = (const float*)d_in[7];
    const float* wo2  = (const float*)d_in[8];
    const float* bo2  = (const float*)d_in[9];
    const float* ln2g = (const float*)d_in[10];
    const float* ln2b = (const float*)d_in[11];
    const float* wq4  = (const float*)d_in[12];
    const float* wk4  = (const float*)d_in[13];
    const float* wv4  = (const float*)d_in[14];
    const float* wo4  = (const float*)d_in[15];
    const float* bo4  = (const float*)d_in[16];
    const float* ln4g = (const float*)d_in[17];
    const float* ln4b = (const float*)d_in[18];
    const float* w_ih = (const float*)d_in[19];
    const float* w_hh = (const float*)d_in[20];
    const float* b_ih = (const float*)d_in[21];
    const float* b_hh = (const float*)d_in[22];
    const float* cg_w = (const float*)d_in[23];
    const float* cg_uw= (const float*)d_in[24];
    const float* cg_ub= (const float*)d_in[25];
    const float* w6   = (const float*)d_in[26];
    const float* b6   = (const float*)d_in[27];
    const float* w7   = (const float*)d_in[28];
    const float* b7   = (const float*)d_in[29];
    const float* rev_w= (const float*)d_in[30];
    const float* rev_b= (const float*)d_in[31];

    int Bn = in_sizes[0] / 1080;
    int grid = (Bn + SB - 1) / SB;
    hipLaunchKernelGGL(se_kernel, dim3(grid), dim3(NTH), 0, stream,
                       x, bn_g, bn_b, bn_m, bn_v, wq2, wk2, wv2, wo2, bo2, ln2g, ln2b,
                       wq4, wk4, wv4, wo4, bo4, ln4g, ln4b,
                       w_ih, w_hh, b_ih, b_hh, cg_w, cg_uw, cg_ub,
                       w6, b6, w7, b7, rev_w, rev_b,
                       (float*)d_out, Bn);
}